// Round 4
// baseline (221.755 us; speedup 1.0000x reference)
//
#include <hip/hip_runtime.h>

// LengthRegulator: B=32, T=512, D=384, DUR_MAX=8, L = 512*7 = 3584
// out[b,f,:] = x[b, idx(f), :] for f < mel_len[b], else 0
// Shapes are fixed by the reference; hard-coded for constant-divisor codegen.

#define B_DIM 32
#define T_DIM 512
#define D_DIM 384
#define L_DIM 3584
#define VEC_PER_ROW 96                 // float4 per row
#define PAIRS_PER_BATCH (L_DIM * VEC_PER_ROW / 2)   // 172032
#define GATHER_BLOCK 256
#define BLOCKS_PER_BATCH (PAIRS_PER_BATCH / GATHER_BLOCK) // 672
#define GATHER_BLOCKS (BLOCKS_PER_BATCH * B_DIM)           // 21504 (%8==0)

typedef float f32x4 __attribute__((ext_vector_type(4)));   // builtin-compatible

__global__ void __launch_bounds__(T_DIM)
lr_build_map(const int* __restrict__ dur, int* __restrict__ idx_map,
             float* __restrict__ mel_out) {
    const int b    = blockIdx.x;
    const int t    = threadIdx.x;          // 0..511
    const int lane = t & 63;
    const int wv   = t >> 6;               // 0..7

    int d = dur[b * T_DIM + t];
    int e = d > 1 ? d : 1;                 // eff in [1,7]

    // wave-level inclusive scan (6 shfl rounds)
    int val = e;
    #pragma unroll
    for (int off = 1; off < 64; off <<= 1) {
        int n = __shfl_up(val, off, 64);
        if (lane >= off) val += n;
    }

    __shared__ int wsum[8];
    if (lane == 63) wsum[wv] = val;
    __syncthreads();

    int base = 0, tot = 0;
    #pragma unroll
    for (int i = 0; i < 8; ++i) {
        int s = wsum[i];
        tot += s;
        if (i < wv) base += s;
    }

    const int cum   = val + base;          // inclusive cumsum
    const int mel   = tot;
    const int start = cum - e;

    int* map_b = idx_map + b * L_DIM;
    for (int k = 0; k < e; ++k)
        map_b[start + k] = t;

    for (int f = mel + t; f < L_DIM; f += T_DIM)
        map_b[f] = -1;

    if (t == 0)
        mel_out[b] = (float)mel;
}

__global__ void __launch_bounds__(GATHER_BLOCK)
lr_gather(const f32x4* __restrict__ x, const int* __restrict__ idx_map,
          f32x4* __restrict__ out) {
    // bijective XCD-chunked swizzle: 21504 blocks, 2688 consecutive per XCD
    // => each XCD covers exactly 4 batches; x working set 3 MiB < 4 MiB L2.
    const int bid = blockIdx.x;
    const int blk = (bid & 7) * (GATHER_BLOCKS / 8) + (bid >> 3);

    const int b    = blk / BLOCKS_PER_BATCH;
    const int pblk = blk - b * BLOCKS_PER_BATCH;
    const int p    = pblk * GATHER_BLOCK + threadIdx.x;  // pair idx in batch
    const int v0   = p << 1;                              // float4 idx in batch
    const int f    = v0 / VEC_PER_ROW;                    // frame (const div)
    const int w    = v0 - f * VEC_PER_ROW;                // even, <= 94

    const int idx = idx_map[b * L_DIM + f];
    f32x4 a = (f32x4)0.f;
    f32x4 c = (f32x4)0.f;
    if (idx >= 0) {
        const f32x4* row = x + ((b * T_DIM + idx) * VEC_PER_ROW);
        a = row[w];
        c = row[w + 1];
    }
    f32x4* o = out + (size_t)(b * L_DIM + f) * VEC_PER_ROW + w;
    __builtin_nontemporal_store(a, o);        // write-only stream: keep L2 for x
    __builtin_nontemporal_store(c, o + 1);
}

extern "C" void kernel_launch(void* const* d_in, const int* in_sizes, int n_in,
                              void* d_out, int out_size, void* d_ws, size_t ws_size,
                              hipStream_t stream) {
    const float* x   = (const float*)d_in[0];
    const int*   dur = (const int*)d_in[1];

    int*   idx_map = (int*)d_ws;                          // 32*3584*4 = 448 KiB
    float* out     = (float*)d_out;
    float* mel_out = out + (size_t)B_DIM * L_DIM * D_DIM; // mel_len tail as f32

    lr_build_map<<<dim3(B_DIM), dim3(T_DIM), 0, stream>>>(dur, idx_map, mel_out);

    lr_gather<<<dim3(GATHER_BLOCKS), dim3(GATHER_BLOCK), 0, stream>>>(
        (const f32x4*)x, idx_map, (f32x4*)out);
}

// Round 5
// 195.646 us; speedup vs baseline: 1.1335x; 1.1335x over previous
//
#include <hip/hip_runtime.h>

// LengthRegulator: B=32, T=512, D=384, DUR_MAX=8, L = 512*7 = 3584
// Row-scatter formulation: each x row is read from HBM exactly once and
// written to its [cum-eff, cum) frame span; zero tail handled by dedicated
// balanced blocks. No idx_map, no dependent gather chain.

#define B_DIM 32
#define T_DIM 512
#define D_DIM 384
#define L_DIM 3584
#define VEC 96                         // f32x4 per row
#define RPB 8                          // rows per scatter block
#define CHUNKS (T_DIM / RPB)           // 64 chunks per batch
#define SCATTER_BLOCKS (B_DIM * CHUNKS)        // 2048
#define TAIL_F0 T_DIM                  // mel >= 512 always (eff >= 1)
#define TAIL_FPB 256                   // frames per tail block
#define TAIL_CHUNKS ((L_DIM - TAIL_F0) / TAIL_FPB)   // 12
#define TAIL_BLOCKS (B_DIM * TAIL_CHUNKS)            // 384
#define TOTAL_BLOCKS (SCATTER_BLOCKS + TAIL_BLOCKS)  // 2432

typedef float f32x4 __attribute__((ext_vector_type(4)));

__global__ void __launch_bounds__(T_DIM)
lr_scan(const int* __restrict__ dur, int* __restrict__ cum_out,
        float* __restrict__ mel_out) {
    const int b    = blockIdx.x;
    const int t    = threadIdx.x;      // 0..511
    const int lane = t & 63;
    const int wv   = t >> 6;

    int d = dur[b * T_DIM + t];
    int e = d > 1 ? d : 1;             // eff in [1,7]

    int val = e;                       // wave inclusive scan (6 shfl rounds)
    #pragma unroll
    for (int off = 1; off < 64; off <<= 1) {
        int n = __shfl_up(val, off, 64);
        if (lane >= off) val += n;
    }

    __shared__ int wsum[8];
    if (lane == 63) wsum[wv] = val;
    __syncthreads();

    int base = 0, tot = 0;
    #pragma unroll
    for (int i = 0; i < 8; ++i) {
        int s = wsum[i];
        tot += s;
        if (i < wv) base += s;
    }

    cum_out[b * T_DIM + t] = val + base;   // inclusive cumsum
    if (t == 0) mel_out[b] = (float)tot;
}

__global__ void __launch_bounds__(256)
lr_write(const f32x4* __restrict__ x, const int* __restrict__ cum,
         f32x4* __restrict__ out) {
    const int blk = blockIdx.x;
    const int tid = threadIdx.x;

    if (blk < SCATTER_BLOCKS) {
        const int b  = blk / CHUNKS;           // const div (64)
        const int c  = blk - b * CHUNKS;
        const int r0 = c * RPB;

        __shared__ f32x4 lx[RPB * VEC];        // 12 KiB: 8 rows
        __shared__ int   scum[RPB + 1];

        if (tid <= RPB) {
            int r = r0 - 1 + tid;
            scum[tid] = (r < 0) ? 0 : cum[b * T_DIM + r];
        }
        const f32x4* xb = x + (b * T_DIM + r0) * VEC;
        #pragma unroll
        for (int i = 0; i < (RPB * VEC) / 256; ++i)     // 3 f4 per thread
            lx[tid + i * 256] = xb[tid + i * 256];
        __syncthreads();

        const int f0 = scum[0];
        const int s1 = scum[1], s2 = scum[2], s3 = scum[3], s4 = scum[4],
                  s5 = scum[5], s6 = scum[6], s7 = scum[7];
        const int span = (scum[RPB] - f0) * VEC;        // f4 count, 768..5376

        f32x4* ob = out + (size_t)(b * L_DIM + f0) * VEC;
        for (int v = tid; v < span; v += 256) {
            const int fr = v / VEC;            // const div (96)
            const int w  = v - fr * VEC;
            const int fa = f0 + fr;
            int r = (fa >= s1) + (fa >= s2) + (fa >= s3) + (fa >= s4)
                  + (fa >= s5) + (fa >= s6) + (fa >= s7);
            ob[v] = lx[r * VEC + w];
        }
    } else {
        const int tb = blk - SCATTER_BLOCKS;
        const int b  = tb / TAIL_CHUNKS;       // const div (12)
        const int c  = tb - b * TAIL_CHUNKS;
        const int mel = cum[b * T_DIM + T_DIM - 1];
        const int fs = TAIL_F0 + c * TAIL_FPB;
        const int lo = fs > mel ? fs : mel;
        const int hi = fs + TAIL_FPB;
        if (lo < hi) {
            const f32x4 z = (f32x4)0.f;
            f32x4* ob = out + (size_t)(b * L_DIM + lo) * VEC;
            const int span = (hi - lo) * VEC;
            for (int v = tid; v < span; v += 256)
                ob[v] = z;
        }
    }
}

extern "C" void kernel_launch(void* const* d_in, const int* in_sizes, int n_in,
                              void* d_out, int out_size, void* d_ws, size_t ws_size,
                              hipStream_t stream) {
    const float* x   = (const float*)d_in[0];
    const int*   dur = (const int*)d_in[1];

    int*   cum     = (int*)d_ws;                          // 32*512*4 = 64 KiB
    float* out     = (float*)d_out;
    float* mel_out = out + (size_t)B_DIM * L_DIM * D_DIM; // mel_len tail as f32

    lr_scan<<<dim3(B_DIM), dim3(T_DIM), 0, stream>>>(dur, cum, mel_out);

    lr_write<<<dim3(TOTAL_BLOCKS), dim3(256), 0, stream>>>(
        (const f32x4*)x, cum, (f32x4*)out);
}

// Round 6
// 193.475 us; speedup vs baseline: 1.1462x; 1.0112x over previous
//
#include <hip/hip_runtime.h>

// LengthRegulator: B=32, T=512, D=384, DUR_MAX=8, L = 512*7 = 3584
// Single fused kernel. Each block = one (batch, chunk-of-8-rows):
//   - redundantly scans its batch's 512 durations (2 KB, L2-resident)
//   - keeps its 8 x rows in REGISTERS (3 f32x4/thread), stores each f4
//     e times into the contiguous frame span [cum-e, cum)
//   - writes a balanced 1/64 slice of the batch's zero tail
// No d_ws, no LDS staging of x, one launch.

#define B_DIM 32
#define T_DIM 512
#define D_DIM 384
#define L_DIM 3584
#define VEC 96                          // f32x4 per row
#define RPB 8                           // rows per block
#define CHUNKS (T_DIM / RPB)            // 64
#define BLOCKS (B_DIM * CHUNKS)         // 2048

typedef float f32x4 __attribute__((ext_vector_type(4)));

__global__ void __launch_bounds__(256)
lr_fused(const f32x4* __restrict__ x, const int* __restrict__ dur,
         f32x4* __restrict__ out, float* __restrict__ mel_out) {
    const int blk  = blockIdx.x;
    const int b    = blk >> 6;          // /CHUNKS
    const int c    = blk & 63;
    const int t    = threadIdx.x;       // 0..255
    const int lane = t & 63;
    const int wv   = t >> 6;            // 0..3

    // ---- full-batch scan of 512 durations (each thread owns rows 2t,2t+1)
    const int2 dd = ((const int2*)(dur + b * T_DIM))[t];
    const int e0 = dd.x > 1 ? dd.x : 1;
    const int e1 = dd.y > 1 ? dd.y : 1;

    int val = e0 + e1;                  // wave inclusive scan of pair-sums
    #pragma unroll
    for (int off = 1; off < 64; off <<= 1) {
        int n = __shfl_up(val, off, 64);
        if (lane >= off) val += n;
    }

    __shared__ int wsum[4];
    __shared__ int scum[T_DIM];         // inclusive cumsum per row (2 KB)
    if (lane == 63) wsum[wv] = val;
    __syncthreads();

    int base = 0, tot = 0;
    #pragma unroll
    for (int i = 0; i < 4; ++i) {
        int w = wsum[i];
        tot += w;
        if (i < wv) base += w;
    }
    const int c1 = val + base;          // cum[2t+1]
    scum[2 * t]     = c1 - e1;
    scum[2 * t + 1] = c1;
    __syncthreads();

    const int mel = tot;                // in [512, 3584]
    if (c == 0 && t == 0)
        mel_out[b] = (float)mel;

    // ---- register-resident scatter of this block's 8 rows
    const int r0 = c * RPB;
    const f32x4* xb   = x + (size_t)(b * T_DIM + r0) * VEC;
    f32x4*       outb = out + (size_t)b * L_DIM * VEC;

    #pragma unroll
    for (int i = 0; i < 3; ++i) {       // 768 f4 / 256 threads
        const int v = t + i * 256;
        const int r = v / VEC;          // 0..7 (const divisor)
        const int w = v - r * VEC;
        const f32x4 xv = xb[v];         // coalesced, read exactly once
        const int gr = r0 + r;
        const int ce = scum[gr];                     // broadcast reads
        const int cs = (gr == 0) ? 0 : scum[gr - 1];
        f32x4* o = outb + (size_t)cs * VEC + w;
        for (int k = cs; k < ce; ++k) { // e in [1,7]; <=2 rows per wave
            *o = xv;
            o += VEC;
        }
    }

    // ---- balanced zero tail: this block writes 1/64 of [mel, L)
    const int tailspan = L_DIM - mel;   // 0..3072
    const int lo = mel + ((tailspan * c) >> 6);
    const int hi = mel + ((tailspan * (c + 1)) >> 6);
    const int n4 = (hi - lo) * VEC;
    const f32x4 z = (f32x4)0.f;
    f32x4* ob = outb + (size_t)lo * VEC;
    for (int v = t; v < n4; v += 256)
        ob[v] = z;
}

extern "C" void kernel_launch(void* const* d_in, const int* in_sizes, int n_in,
                              void* d_out, int out_size, void* d_ws, size_t ws_size,
                              hipStream_t stream) {
    const float* x   = (const float*)d_in[0];
    const int*   dur = (const int*)d_in[1];

    float* out     = (float*)d_out;
    float* mel_out = out + (size_t)B_DIM * L_DIM * D_DIM; // mel_len tail as f32

    lr_fused<<<dim3(BLOCKS), dim3(256), 0, stream>>>(
        (const f32x4*)x, dur, (f32x4*)out, mel_out);
}